// Round 7
// baseline (74.938 us; speedup 1.0000x reference)
//
#include <hip/hip_runtime.h>
#include <hip/hip_bf16.h>

#define NUM_NODES 100000
#define BATCH 4096
#define NNB 64
#define HID 128
#define NHEAD 8
#define HDIM 16
#define TDIM 64
#define RDIM 64
#define START_TC 0.2f
#define END_TC 0.8f
#define NORMS 0.25f

typedef __attribute__((ext_vector_type(4))) float f32x4;
typedef __attribute__((ext_vector_type(8))) short bf16x8;

#define AST 136   // A-tile row stride in shorts (272B: 16B-aligned rows)
#define KST 130   // K tile row stride in shorts (260B: stride/4 % 32 == 1 -> ~conflict-free row reads)
#define APAD 9    // attn_t row stride in floats (odd -> conflict-free scalar writes/reads)

__device__ __forceinline__ short f2bs(float f) {
    unsigned u = __float_as_uint(f);
    u += 0x7fffu + ((u >> 16) & 1u);   // RNE
    return (short)(u >> 16);
}

// Pack weights into MFMA B-fragment order, combined biases, and q0 = t_q(START_T).
__global__ void prep_kernel(const float* __restrict__ t2v_w, const float* __restrict__ t2v_b,
                            const float* __restrict__ tW_k, const float* __restrict__ tb_k,
                            const float* __restrict__ tW_q, const float* __restrict__ tb_q,
                            const float* __restrict__ tW_v, const float* __restrict__ tb_v,
                            const float* __restrict__ rW_k, const float* __restrict__ rb_k,
                            const float* __restrict__ rW_v, const float* __restrict__ rb_v,
                            short* __restrict__ wfrag, float* __restrict__ bias_kv,
                            float* __restrict__ q0_add)
{
    int blk = blockIdx.x, t = threadIdx.x;
    if (blk < 128) {
        // wfrag[((kt*16+nt)*64 + lane)*8 + i] = W[kt*32 + (lane>>4)*8 + i][nt*16 + (lane&15)]
        int idx = blk * 256 + t;
        int i   = idx & 7;
        int ln  = (idx >> 3) & 63;
        int nt  = (idx >> 9) & 15;
        int kt  = idx >> 13;
        int k = kt * 32 + (ln >> 4) * 8 + i;
        int c = nt * 16 + (ln & 15);
        int cc = (c < HID) ? c : c - HID;
        float val;
        if (k < TDIM) val = (c < HID) ? tW_k[k*HID + cc] : tW_v[k*HID + cc];
        else          val = (c < HID) ? rW_k[(k-TDIM)*HID + cc] : rW_v[(k-TDIM)*HID + cc];
        wfrag[idx] = f2bs(val);
    } else if (blk == 128) {
        bias_kv[t] = (t < HID) ? (tb_k[t] + rb_k[t]) : (tb_v[t-HID] + rb_v[t-HID]);
    } else if (t < HID) {
        float s = tb_q[t];
        for (int j = 0; j < TDIM; ++j) {
            float f = START_TC * t2v_w[j] + t2v_b[j];
            float tv = (j == 0) ? f : __sinf(f);
            s += tv * tW_q[j*HID + t];
        }
        q0_add[t] = s;
    }
}

// 512 threads = 8 waves. Wave w owns output cols 32(w&3).. for k (w<4) / v (w>=4).
// Gathers issued at T0 (depend only on neighbors), consumed after GEMM ->
// latency hidden under t2v + barrier + GEMM. launch_bounds(512,4): reg cap 128
// (structural ~104 VGPR + 32 AGPR acc) -> 2 blocks/CU, no spill.
__launch_bounds__(512, 4)
__global__ void aggr_kernel(const float* __restrict__ k_tab, const float* __restrict__ q_tab,
                            const float* __restrict__ v_tab,
                            const int* __restrict__ nid, const int* __restrict__ neighbors,
                            const float* __restrict__ times, const float* __restrict__ rels,
                            const float* __restrict__ t2v_w, const float* __restrict__ t2v_b,
                            const short* __restrict__ wfrag, const float* __restrict__ bias_kv,
                            const float* __restrict__ q0_add, float* __restrict__ out)
{
    // A-tile (GEMM input) is dead after phase 2; Ksh reuses the same LDS.
    __shared__ __align__(16) short AK[64 * AST];
    __shared__ float q_lds[HID];
    __shared__ float maskadd[NNB];
    __shared__ float attn_t[NNB][APAD];   // [n][head]
    __shared__ int   anyvalid;

    short* A   = AK;   // stride AST, phases 1-2
    short* Ksh = AK;   // stride KST, phases 3-4

    const int b = blockIdx.x;
    const int t = threadIdx.x;
    const int w = t >> 6;   // wave 0..7
    const int l = t & 63;   // lane
    const int cw = (w & 3) * 32;

    // ---- early issue: all global loads, longest-latency-consumed-last order ----
    // (1) loads consumed BEFORE the first barrier: times / rels / q
    float tt;
    f32x4 r0, r1, r2, r3;
    if (w < 4) {
        tt = times[b*NNB + l];
    } else {
        const float* rp = rels + ((size_t)b*NNB + l)*RDIM + (w - 4)*16;
        r0 = *(const f32x4*)(rp);
        r1 = *(const f32x4*)(rp + 4);
        r2 = *(const f32x4*)(rp + 8);
        r3 = *(const f32x4*)(rp + 12);
    }
    f32x4 qa, qb;
    if (w == 1 && l < 32) {
        int q_node = nid[b];
        qa = *(const f32x4*)(q_tab + (size_t)q_node*HID + l*4);
        qb = *(const f32x4*)(q0_add + l*4);
    }
    // (2) neighbor indices (coalesced; one per lane, distributed via shfl)
    int nb = neighbors[b*NNB + l];
    // (3) gather k/v table rows -> registers; consumed only in phase 3
    const float* tab = (w < 4) ? k_tab : v_tab;
    float g[2][4][4];
    #pragma unroll
    for (int mt = 0; mt < 4; ++mt) {
        #pragma unroll
        for (int i = 0; i < 4; ++i) {
            int n = mt*16 + ((l >> 4) << 2) + i;
            int row = __shfl(nb, n);
            const float* tr = tab + (size_t)row*HID + cw + (l & 15);
            g[0][mt][i] = tr[0];
            g[1][mt][i] = tr[16];
        }
    }

    // ---- phase 0: mask / anyvalid (wave 0) + q store (wave 1) ----
    if (t < 64) {
        bool valid = (tt >= START_TC) && (tt < END_TC);
        maskadd[t] = valid ? 0.f : -1e30f;
        unsigned long long bal = __ballot(valid);
        if (t == 0) anyvalid = (bal != 0ull) ? 1 : 0;
    }
    if (w == 1 && l < 32)
        *(f32x4*)(q_lds + l*4) = qa + qb;

    // ---- phase 1: stage A-tile = [t2v(times) | rels], wave-specialized ----
    if (w < 4) {
        int c0 = w * 16;
        bf16x8 v0, v1;
        #pragma unroll
        for (int u = 0; u < 8; ++u) {
            int j = c0 + u;
            float f = fmaf(tt, t2v_w[j], t2v_b[j]);
            v0[u] = f2bs((j == 0) ? f : __sinf(f));
        }
        #pragma unroll
        for (int u = 0; u < 8; ++u) {
            int j = c0 + 8 + u;
            float f = fmaf(tt, t2v_w[j], t2v_b[j]);
            v1[u] = f2bs(__sinf(f));
        }
        *(bf16x8*)(&A[l*AST + c0])     = v0;
        *(bf16x8*)(&A[l*AST + c0 + 8]) = v1;
    } else {
        int s = w - 4;
        bf16x8 o0, o1;
        #pragma unroll
        for (int e = 0; e < 4; ++e) {
            o0[e]   = f2bs(r0[e]);  o0[e+4] = f2bs(r1[e]);
            o1[e]   = f2bs(r2[e]);  o1[e+4] = f2bs(r3[e]);
        }
        *(bf16x8*)(&A[l*AST + TDIM + s*16])     = o0;
        *(bf16x8*)(&A[l*AST + TDIM + s*16 + 8]) = o1;
    }
    __syncthreads();

    // ---- phase 2: GEMM [64x128] @ [128x256]; wave w owns cols 32w..32w+31 ----
    f32x4 acc[4][2];
    #pragma unroll
    for (int mt = 0; mt < 4; ++mt)
        #pragma unroll
        for (int j = 0; j < 2; ++j)
            acc[mt][j] = (f32x4){0.f, 0.f, 0.f, 0.f};

    const bf16x8* wf = (const bf16x8*)wfrag;
    #pragma unroll
    for (int kt = 0; kt < 4; ++kt) {
        bf16x8 af[4], bfrag[2];
        int kcol = kt*32 + (l >> 4)*8;
        #pragma unroll
        for (int mt = 0; mt < 4; ++mt)
            af[mt] = *(const bf16x8*)(&A[(mt*16 + (l & 15))*AST + kcol]);
        #pragma unroll
        for (int j = 0; j < 2; ++j)
            bfrag[j] = wf[(kt*16 + (2*w + j))*64 + l];
        #pragma unroll
        for (int mt = 0; mt < 4; ++mt)
            #pragma unroll
            for (int j = 0; j < 2; ++j)
                acc[mt][j] = __builtin_amdgcn_mfma_f32_16x16x32_bf16(af[mt], bfrag[j], acc[mt][j], 0, 0, 0);
    }
    __syncthreads();   // A is dead; Ksh may now overwrite it

    // ---- phase 3: consume gathered rows + bias.
    // waves 0-3: k -> bf16 Ksh (LDS). waves 4-7: v stays f32 in acc registers.
    {
        float biasr[2];
        #pragma unroll
        for (int j = 0; j < 2; ++j)
            biasr[j] = bias_kv[((w >= 4) ? HID : 0) + cw + j*16 + (l & 15)];
        if (w < 4) {
            #pragma unroll
            for (int mt = 0; mt < 4; ++mt) {
                #pragma unroll
                for (int i = 0; i < 4; ++i) {
                    int n = mt*16 + ((l >> 4) << 2) + i;
                    #pragma unroll
                    for (int j = 0; j < 2; ++j) {
                        int col = cw + j*16 + (l & 15);
                        Ksh[n*KST + col] = f2bs(acc[mt][j][i] + biasr[j] + g[j][mt][i]);
                    }
                }
            }
        } else {
            #pragma unroll
            for (int mt = 0; mt < 4; ++mt)
                #pragma unroll
                for (int i = 0; i < 4; ++i)
                    #pragma unroll
                    for (int j = 0; j < 2; ++j)
                        acc[mt][j][i] += biasr[j] + g[j][mt][i];
        }
    }
    __syncthreads();

    // ---- phase 4: scores + softmax. lane l = neighbor l; wave w = head (w&7) ----
    {
        const short* krow = &Ksh[l*KST + w*16];   // w in 0..7 = head
        float s = 0.f;
        #pragma unroll
        for (int e = 0; e < 8; ++e) {
            unsigned u = *(const unsigned*)(&krow[2*e]);
            float k0 = __uint_as_float(u << 16);
            float k1 = __uint_as_float(u & 0xffff0000u);
            s = fmaf(q_lds[w*16 + 2*e],     k0, s);
            s = fmaf(q_lds[w*16 + 2*e + 1], k1, s);
        }
        float sc = s * NORMS + maskadd[l];
        float m = sc;
        #pragma unroll
        for (int off = 1; off <= 32; off <<= 1)
            m = fmaxf(m, __shfl_xor(m, off));
        float e = __expf(sc - m);
        float sum = e;
        #pragma unroll
        for (int off = 1; off <= 32; off <<= 1)
            sum += __shfl_xor(sum, off);
        attn_t[l][w] = e / sum;
    }
    __syncthreads();

    // ---- phase 5: PV in registers (waves 4-7 hold v) + cross-group reduce ----
    if (w >= 4) {
        int gq = w - 4;
        float p[2] = {0.f, 0.f};
        #pragma unroll
        for (int mt = 0; mt < 4; ++mt) {
            #pragma unroll
            for (int i = 0; i < 4; ++i) {
                int n = mt*16 + ((l >> 4) << 2) + i;
                #pragma unroll
                for (int j = 0; j < 2; ++j)
                    p[j] = fmaf(attn_t[n][2*gq + j], acc[mt][j][i], p[j]);
            }
        }
        #pragma unroll
        for (int j = 0; j < 2; ++j) {
            p[j] += __shfl_xor(p[j], 16);
            p[j] += __shfl_xor(p[j], 32);
        }
        if (l < 16) {
            #pragma unroll
            for (int j = 0; j < 2; ++j) {
                int col = gq*32 + j*16 + l;
                out[(size_t)b*HID + col] = anyvalid ? p[j] : 0.f;
            }
        }
    }
}

extern "C" void kernel_launch(void* const* d_in, const int* in_sizes, int n_in,
                              void* d_out, int out_size, void* d_ws, size_t ws_size,
                              hipStream_t stream)
{
    const float* k_tab = (const float*)d_in[0];
    const float* q_tab = (const float*)d_in[1];
    const float* v_tab = (const float*)d_in[2];
    const int*   nid   = (const int*)d_in[3];
    const int*   neighbors = (const int*)d_in[4];
    const float* times = (const float*)d_in[5];
    const float* rels  = (const float*)d_in[6];
    const float* t2v_w = (const float*)d_in[7];
    const float* t2v_b = (const float*)d_in[8];
    const float* tW_k  = (const float*)d_in[9];
    const float* tb_k  = (const float*)d_in[10];
    const float* tW_q  = (const float*)d_in[11];
    const float* tb_q  = (const float*)d_in[12];
    const float* tW_v  = (const float*)d_in[13];
    const float* tb_v  = (const float*)d_in[14];
    const float* rW_k  = (const float*)d_in[15];
    const float* rb_k  = (const float*)d_in[16];
    const float* rW_v  = (const float*)d_in[17];
    const float* rb_v  = (const float*)d_in[18];

    short* wfrag   = (short*)d_ws;                          // 32768 bf16 = 64KB
    float* bias_kv = (float*)((char*)d_ws + 65536);         // 256 f32
    float* q0_add  = (float*)((char*)d_ws + 65536 + 1024);  // 128 f32

    prep_kernel<<<130, 256, 0, stream>>>(t2v_w, t2v_b, tW_k, tb_k, tW_q, tb_q,
                                         tW_v, tb_v, rW_k, rb_k, rW_v, rb_v,
                                         wfrag, bias_kv, q0_add);
    aggr_kernel<<<BATCH, 512, 0, stream>>>(k_tab, q_tab, v_tab, nid, neighbors,
                                           times, rels, t2v_w, t2v_b,
                                           wfrag, bias_kv, q0_add, (float*)d_out);
}